// Round 3
// baseline (972.264 us; speedup 1.0000x reference)
//
#include <hip/hip_runtime.h>

#define BB 512
#define TT 1024
#define KK 48
#define HF 24
#define NINF (-1e30f)

__device__ __forceinline__ float rlane(float v, int l) {
    return __int_as_float(__builtin_amdgcn_readlane(__float_as_int(v), l));
}
__device__ __forceinline__ float rfirst(float v) {
    return __int_as_float(__builtin_amdgcn_readfirstlane(__float_as_int(v)));
}

// One block per batch, 4 waves:
//   wid 0,1: forward scan, source-states split [0,24) / [24,48)  -> ws[b]
//   wid 2,3: viterbi scan, same split; wave 2 writes bp + backtracks.
// One __syncthreads per step (double-buffered partial exchange).
__global__ __launch_bounds__(256, 1) void crf_main(
    const float* __restrict__ em,    // [B][T][K]
    const int*   __restrict__ tags,  // [B][T]
    const float* __restrict__ st,    // [K]
    const float* __restrict__ en,    // [K]
    const float* __restrict__ tr,    // [K][K]
    float* __restrict__ out,         // [1 + B*T]
    float* __restrict__ ws)          // [B]
{
    __shared__ unsigned char s_bp[TT][KK];   // 49152 B (row 0 unused)
    __shared__ unsigned char s_path[TT];     // 1024 B
    __shared__ float s_z [2][2][64];         // fwd partial sums
    __shared__ float s_pm[2][2][64];         // vit partial max
    __shared__ int   s_pi[2][2][64];         // vit partial argmax

    const int b    = blockIdx.x;
    const int tid  = threadIdx.x;
    const int lane = tid & 63;
    const int wid  = tid >> 6;
    const int half = wid & 1;        // which 24 source states this wave owns
    const int ibase = half * HF;

    const float* emb = em + (size_t)b * TT * KK;
    const int*   tgb = tags + (size_t)b * TT;

    // sequence length (mask is a contiguous prefix) — uniform across block
    int cnt = 0;
    for (int t = lane; t < TT; t += 64) cnt += (tgb[t] > -1) ? 1 : 0;
#pragma unroll
    for (int off = 32; off >= 1; off >>= 1) cnt += __shfl_xor(cnt, off);
    const int len = cnt;  // >= 1

    const bool act = lane < KK;
    const int  jj  = act ? lane : (KK - 1);

    if (wid < 2) {
        // =================== forward (log-partition) ===================
        float eTc[HF];  // exp(T[ibase+i][j])
#pragma unroll
        for (int i = 0; i < HF; ++i) eTc[i] = __expf(tr[(ibase + i) * KK + jj]);

        float score = 0.f;
        if (wid == 0) {
            // gold path score: pure gather, t-parallel across lanes
            float sc = 0.f;
            for (int t = lane; t < len; t += 64) {
                int tg = tgb[t];
                sc += emb[t * KK + tg];
                if (t > 0) sc += tr[tgb[t - 1] * KK + tg];
            }
#pragma unroll
            for (int off = 32; off >= 1; off >>= 1) sc += __shfl_xor(sc, off);
            score = sc + st[tgb[0]] + en[tgb[len - 1]];
        }

        float a     = act ? (st[jj] + emb[jj]) : NINF;
        float e_cur = (len > 1) ? emb[KK + jj]     : 0.f;
        float e_n1  = (len > 2) ? emb[2 * KK + jj] : 0.f;

        for (int t = 1; t < len; ++t) {
            float e_n2 = (t + 2 < len) ? emb[(t + 2) * KK + jj] : 0.f;
            const int p = t & 1;

            float c  = rfirst(a);          // identical in both fwd waves
            float ea = __expf(a - c);      // inactive lanes: 0

            float z0 = 0.f, z1 = 0.f, z2 = 0.f, z3 = 0.f;
#pragma unroll
            for (int q = 0; q < 6; ++q) {
                z0 = fmaf(rlane(ea, ibase + 4 * q + 0), eTc[4 * q + 0], z0);
                z1 = fmaf(rlane(ea, ibase + 4 * q + 1), eTc[4 * q + 1], z1);
                z2 = fmaf(rlane(ea, ibase + 4 * q + 2), eTc[4 * q + 2], z2);
                z3 = fmaf(rlane(ea, ibase + 4 * q + 3), eTc[4 * q + 3], z3);
            }
            float zw = (z0 + z1) + (z2 + z3);

            s_z[p][half][lane] = zw;
            __syncthreads();
            float zo = s_z[p][half ^ 1][lane];
            float z  = half ? (zo + zw) : (zw + zo);   // both = z_lo + z_hi

            a = act ? (c + __logf(z) + e_cur) : NINF;
            e_cur = e_n1; e_n1 = e_n2;
        }

        if (wid == 0) {
            // log_z = logsumexp(alpha + end)
            float v = act ? (a + en[jj]) : NINF;
            float M = v;
#pragma unroll
            for (int off = 32; off >= 1; off >>= 1) M = fmaxf(M, __shfl_xor(M, off));
            float sx = act ? __expf(v - M) : 0.f;
#pragma unroll
            for (int off = 32; off >= 1; off >>= 1) sx += __shfl_xor(sx, off);
            float logz = M + __logf(sx);
            if (lane == 0) ws[b] = score - logz;
        }
    } else {
        // =================== viterbi (bit-exact) ===================
        float Tc[HF];  // T[ibase+i][j]
#pragma unroll
        for (int i = 0; i < HF; ++i) Tc[i] = tr[(ibase + i) * KK + jj];

        float a     = act ? (st[jj] + emb[jj]) : NINF;
        float e_cur = (len > 1) ? emb[KK + jj]     : 0.f;
        float e_n1  = (len > 2) ? emb[2 * KK + jj] : 0.f;

        for (int t = 1; t < len; ++t) {
            float e_n2 = (t + 2 < len) ? emb[(t + 2) * KK + jj] : 0.f;
            const int p = t & 1;

            float x[HF];
#pragma unroll
            for (int i = 0; i < HF; ++i) x[i] = rlane(a, ibase + i) + Tc[i];

            // partial max over this half (exact: fmaxf only)
            float l1[8];
#pragma unroll
            for (int q = 0; q < 8; ++q)
                l1[q] = fmaxf(fmaxf(x[3 * q], x[3 * q + 1]), x[3 * q + 2]);
            float l2a = fmaxf(fmaxf(l1[0], l1[1]), l1[2]);
            float l2b = fmaxf(fmaxf(l1[3], l1[4]), l1[5]);
            float pm  = fmaxf(fmaxf(l2a, l2b), fmaxf(l1[6], l1[7]));

            // partial first-occurrence argmax (absolute index)
            int c0 = 1 << 30, c1 = 1 << 30;
#pragma unroll
            for (int q = 11; q >= 0; --q) {
                c0 = (x[q]      == pm) ? (ibase + q)      : c0;
                c1 = (x[q + 12] == pm) ? (ibase + q + 12) : c1;
            }
            int pidx = min(c0, c1);

            s_pm[p][half][lane] = pm;
            s_pi[p][half][lane] = pidx;
            __syncthreads();

            float pmLo, pmHi; int piLo, piHi;
            if (half == 0) { pmLo = pm; piLo = pidx;
                             pmHi = s_pm[p][1][lane]; piHi = s_pi[p][1][lane]; }
            else           { pmHi = pm; piHi = pidx;
                             pmLo = s_pm[p][0][lane]; piLo = s_pi[p][0][lane]; }
            bool hi = pmHi > pmLo;           // tie -> lower half (first occurrence)
            float M = hi ? pmHi : pmLo;
            int  idx = hi ? piHi : piLo;

            a = act ? (M + e_cur) : NINF;
            if (half == 0 && act) s_bp[t][lane] = (unsigned char)idx;
            e_cur = e_n1; e_n1 = e_n2;
        }

        if (half == 0) {  // wave 2: backtrack + tag write
            // best last tag = argmax(alpha + end), first occurrence
            float v = act ? (a + en[jj]) : NINF;
            float M = v;
#pragma unroll
            for (int off = 32; off >= 1; off >>= 1) M = fmaxf(M, __shfl_xor(M, off));
            unsigned long long msk = __ballot(v == M);
            int cur = __ffsll(msk) - 1;
            if (lane == 0) s_path[len - 1] = (unsigned char)cur;

            // register-row backtrack: lane l holds bp[t][l]; serial step is a
            // readlane (VALU) instead of a dependent LDS read. 8-row batches.
            int t = len - 1;
            while (t >= 1) {
                const int n = (t < 8) ? t : 8;
                unsigned r[8];
#pragma unroll
                for (int k = 0; k < 8; ++k)
                    r[k] = (k < n && act) ? (unsigned)s_bp[t - k][lane] : 0u;
#pragma unroll
                for (int k = 0; k < 8; ++k) {
                    if (k < n) {
                        cur = __builtin_amdgcn_readlane((int)r[k], cur);
                        if (lane == 0) s_path[t - k - 1] = (unsigned char)cur;
                    }
                }
                t -= n;
            }

            float* ob = out + 1 + (size_t)b * TT;
            for (int tt = lane; tt < TT; tt += 64)
                ob[tt] = (tt < len) ? (float)s_path[tt] : -1.0f;
        }
    }
}

__global__ __launch_bounds__(512) void loss_reduce(const float* __restrict__ ws,
                                                   float* __restrict__ out)
{
    __shared__ float sh[8];
    const int lane = threadIdx.x & 63;
    const int w    = threadIdx.x >> 6;
    float s = ws[threadIdx.x];  // B == 512 == blockDim
#pragma unroll
    for (int off = 32; off >= 1; off >>= 1) s += __shfl_xor(s, off);
    if (lane == 0) sh[w] = s;
    __syncthreads();
    if (threadIdx.x == 0) {
        float tot = 0.f;
        for (int i = 0; i < 8; ++i) tot += sh[i];
        out[0] = -tot;
    }
}

extern "C" void kernel_launch(void* const* d_in, const int* in_sizes, int n_in,
                              void* d_out, int out_size, void* d_ws, size_t ws_size,
                              hipStream_t stream)
{
    const float* em   = (const float*)d_in[0];
    const int*   tags = (const int*)d_in[1];
    const float* st   = (const float*)d_in[2];
    const float* en   = (const float*)d_in[3];
    const float* tr   = (const float*)d_in[4];
    float* out = (float*)d_out;
    float* wsf = (float*)d_ws;

    hipLaunchKernelGGL(crf_main, dim3(BB), dim3(256), 0, stream,
                       em, tags, st, en, tr, out, wsf);
    hipLaunchKernelGGL(loss_reduce, dim3(1), dim3(512), 0, stream, wsf, out);
}

// Round 4
// 642.116 us; speedup vs baseline: 1.5142x; 1.5142x over previous
//
#include <hip/hip_runtime.h>

#define BB 512
#define TT 1024
#define KK 48
#define NINF (-1e30f)

__device__ __forceinline__ float rlane(float v, int l) {
    return __int_as_float(__builtin_amdgcn_readlane(__float_as_int(v), l));
}
__device__ __forceinline__ float rfirst(float v) {
    return __int_as_float(__builtin_amdgcn_readfirstlane(__float_as_int(v)));
}

// One block per batch. Wave 0: forward (log-partition + gold score -> ws[b]).
// Wave 1: Viterbi (backpointers in LDS, backtrack, write tags to out[1..]).
// No __syncthreads: waves are independent. Emission loads are prefetched at
// distance 4 through a statically-indexed 4-slot register buffer (unroll-4).
__global__ __launch_bounds__(128, 1) void crf_main(
    const float* __restrict__ em,    // [B][T][K]
    const int*   __restrict__ tags,  // [B][T]
    const float* __restrict__ st,    // [K]
    const float* __restrict__ en,    // [K]
    const float* __restrict__ tr,    // [K][K]
    float* __restrict__ out,         // [1 + B*T]
    float* __restrict__ ws)          // [B]
{
    __shared__ unsigned char s_bp[TT][KK];      // 49152 B (row 0 unused)
    __shared__ unsigned char s_path[TT];        // 1024 B

    const int b    = blockIdx.x;
    const int tid  = threadIdx.x;
    const int lane = tid & 63;
    const int wid  = tid >> 6;

    const float* emb = em + (size_t)b * TT * KK;
    const int*   tgb = tags + (size_t)b * TT;

    // sequence length (mask is a contiguous prefix)
    int cnt = 0;
    for (int t = lane; t < TT; t += 64) cnt += (tgb[t] > -1) ? 1 : 0;
#pragma unroll
    for (int off = 32; off >= 1; off >>= 1) cnt += __shfl_xor(cnt, off);
    const int len = cnt;  // >= 1

    const bool act = lane < KK;
    const int  jj  = act ? lane : (KK - 1);

    const int S    = len - 1;      // number of scan steps
    const int nblk = S >> 2;
    const int rem  = S & 3;

    if (wid == 0) {
        // ---- gold path score: pure gather, t-parallel across lanes ----
        float sc = 0.f;
        for (int t = lane; t < len; t += 64) {
            int tg = tgb[t];
            sc += emb[t * KK + tg];
            if (t > 0) sc += tr[tgb[t - 1] * KK + tg];
        }
#pragma unroll
        for (int off = 32; off >= 1; off >>= 1) sc += __shfl_xor(sc, off);
        float score = sc + st[tgb[0]] + en[tgb[len - 1]];  // lane-uniform

        // ---- forward scan: log-partition ----
        float eTc[KK];  // exp(T[:, j]) register column
#pragma unroll
        for (int i = 0; i < KK; ++i) eTc[i] = __expf(tr[i * KK + jj]);

        float a = act ? (st[jj] + emb[jj]) : NINF;

        float e[4];
#pragma unroll
        for (int k = 0; k < 4; ++k) {
            int tn = 1 + k; tn = (tn < len) ? tn : (len - 1);
            e[k] = emb[(size_t)tn * KK + jj];
        }

#define FSTEP(t_, k_) {                                                      \
        float c  = rfirst(a);  /* center; spread bounded, exp args safe */   \
        float ea = __expf(a - c);  /* inactive lanes: exp(-inf)=0 */         \
        float z0 = 0.f, z1 = 0.f, z2 = 0.f, z3 = 0.f;                        \
        _Pragma("unroll")                                                    \
        for (int q = 0; q < 12; ++q) {                                       \
            z0 = fmaf(rlane(ea, 4 * q + 0), eTc[4 * q + 0], z0);             \
            z1 = fmaf(rlane(ea, 4 * q + 1), eTc[4 * q + 1], z1);             \
            z2 = fmaf(rlane(ea, 4 * q + 2), eTc[4 * q + 2], z2);             \
            z3 = fmaf(rlane(ea, 4 * q + 3), eTc[4 * q + 3], z3);             \
        }                                                                    \
        a = act ? (c + __logf((z0 + z1) + (z2 + z3)) + e[k_]) : NINF;        \
        int tn = (t_) + 4; tn = (tn < len) ? tn : (len - 1);                 \
        e[k_] = emb[(size_t)tn * KK + jj];                                   \
    }

        for (int u = 0; u < nblk; ++u) {
            int t = 4 * u + 1;
            FSTEP(t, 0) FSTEP(t + 1, 1) FSTEP(t + 2, 2) FSTEP(t + 3, 3)
        }
        {
            int t = (nblk << 2) + 1;
            if (rem > 0) FSTEP(t, 0)
            if (rem > 1) FSTEP(t + 1, 1)
            if (rem > 2) FSTEP(t + 2, 2)
        }
#undef FSTEP

        // log_z = logsumexp(alpha + end)
        float v = act ? (a + en[jj]) : NINF;
        float M = v;
#pragma unroll
        for (int off = 32; off >= 1; off >>= 1) M = fmaxf(M, __shfl_xor(M, off));
        float sx = act ? __expf(v - M) : 0.f;
#pragma unroll
        for (int off = 32; off >= 1; off >>= 1) sx += __shfl_xor(sx, off);
        float logz = M + __logf(sx);
        if (lane == 0) ws[b] = score - logz;
    } else {
        // ---------------- viterbi (bit-exact vs reference) ----------------
        float Tc[KK];  // raw T[:, j] register column
#pragma unroll
        for (int i = 0; i < KK; ++i) Tc[i] = tr[i * KK + jj];

        float a = act ? (st[jj] + emb[jj]) : NINF;

        float e[4];
#pragma unroll
        for (int k = 0; k < 4; ++k) {
            int tn = 1 + k; tn = (tn < len) ? tn : (len - 1);
            e[k] = emb[(size_t)tn * KK + jj];
        }

#define VSTEP(t_, k_) {                                                      \
        float x[KK];                                                         \
        _Pragma("unroll")                                                    \
        for (int i = 0; i < KK; ++i) x[i] = rlane(a, i) + Tc[i];             \
        float l1[16];                                                        \
        _Pragma("unroll")                                                    \
        for (int q = 0; q < 16; ++q)                                         \
            l1[q] = fmaxf(fmaxf(x[3 * q], x[3 * q + 1]), x[3 * q + 2]);      \
        float l2[6];                                                         \
        _Pragma("unroll")                                                    \
        for (int q = 0; q < 5; ++q)                                          \
            l2[q] = fmaxf(fmaxf(l1[3 * q], l1[3 * q + 1]), l1[3 * q + 2]);   \
        l2[5] = l1[15];                                                      \
        float M = fmaxf(fmaxf(fmaxf(l2[0], l2[1]), l2[2]),                   \
                        fmaxf(fmaxf(l2[3], l2[4]), l2[5]));                  \
        int bi0 = 255, bi1 = 255, bi2 = 255, bi3 = 255;                      \
        _Pragma("unroll")                                                    \
        for (int i = 11; i >= 0; --i) {                                      \
            bi0 = (x[i]      == M) ? (i)      : bi0;                         \
            bi1 = (x[i + 12] == M) ? (i + 12) : bi1;                         \
            bi2 = (x[i + 24] == M) ? (i + 24) : bi2;                         \
            bi3 = (x[i + 36] == M) ? (i + 36) : bi3;                         \
        }                                                                    \
        int bi = min(min(bi0, bi1), min(bi2, bi3));                          \
        a = act ? (M + e[k_]) : NINF;                                        \
        if (act) s_bp[t_][lane] = (unsigned char)bi;                         \
        int tn = (t_) + 4; tn = (tn < len) ? tn : (len - 1);                 \
        e[k_] = emb[(size_t)tn * KK + jj];                                   \
    }

        for (int u = 0; u < nblk; ++u) {
            int t = 4 * u + 1;
            VSTEP(t, 0) VSTEP(t + 1, 1) VSTEP(t + 2, 2) VSTEP(t + 3, 3)
        }
        {
            int t = (nblk << 2) + 1;
            if (rem > 0) VSTEP(t, 0)
            if (rem > 1) VSTEP(t + 1, 1)
            if (rem > 2) VSTEP(t + 2, 2)
        }
#undef VSTEP

        // best last tag = argmax(alpha + end), first occurrence
        float v = act ? (a + en[jj]) : NINF;
        float M = v;
#pragma unroll
        for (int off = 32; off >= 1; off >>= 1) M = fmaxf(M, __shfl_xor(M, off));
        unsigned long long msk = __ballot(v == M);
        int cur = __ffsll(msk) - 1;
        s_path[len - 1] = (unsigned char)cur;

        // register-row backtrack: lane l holds bp[t][l]; the serial step is a
        // readlane (VALU) instead of a dependent LDS load. 8-row batches.
        int t = len - 1;
        while (t >= 1) {
            const int n = (t < 8) ? t : 8;
            unsigned r[8];
#pragma unroll
            for (int k = 0; k < 8; ++k)
                r[k] = (k < n && act) ? (unsigned)s_bp[t - k][lane] : 0u;
#pragma unroll
            for (int k = 0; k < 8; ++k) {
                if (k < n) {
                    cur = __builtin_amdgcn_readlane((int)r[k], cur);
                    if (lane == 0) s_path[t - k - 1] = (unsigned char)cur;
                }
            }
            t -= n;
        }

        // write tags (as floats; -1 where masked)
        float* ob = out + 1 + (size_t)b * TT;
        for (int tt = lane; tt < TT; tt += 64)
            ob[tt] = (tt < len) ? (float)s_path[tt] : -1.0f;
    }
}

__global__ __launch_bounds__(512) void loss_reduce(const float* __restrict__ ws,
                                                   float* __restrict__ out)
{
    __shared__ float sh[8];
    const int lane = threadIdx.x & 63;
    const int w    = threadIdx.x >> 6;
    float s = ws[threadIdx.x];  // B == 512 == blockDim
#pragma unroll
    for (int off = 32; off >= 1; off >>= 1) s += __shfl_xor(s, off);
    if (lane == 0) sh[w] = s;
    __syncthreads();
    if (threadIdx.x == 0) {
        float tot = 0.f;
        for (int i = 0; i < 8; ++i) tot += sh[i];
        out[0] = -tot;
    }
}

extern "C" void kernel_launch(void* const* d_in, const int* in_sizes, int n_in,
                              void* d_out, int out_size, void* d_ws, size_t ws_size,
                              hipStream_t stream)
{
    const float* em   = (const float*)d_in[0];
    const int*   tags = (const int*)d_in[1];
    const float* st   = (const float*)d_in[2];
    const float* en   = (const float*)d_in[3];
    const float* tr   = (const float*)d_in[4];
    float* out = (float*)d_out;
    float* wsf = (float*)d_ws;

    hipLaunchKernelGGL(crf_main, dim3(BB), dim3(128), 0, stream,
                       em, tags, st, en, tr, out, wsf);
    hipLaunchKernelGGL(loss_reduce, dim3(1), dim3(512), 0, stream, wsf, out);
}